// Round 6
// baseline (345.285 us; speedup 1.0000x reference)
//
#include <hip/hip_runtime.h>
#include <math.h>

#define B 8
#define S 1024
#define HID 768
#define RH 384
#define NH 6
#define HD 64
#define KW 9
#define KNH 54
#define OUTHALF 384
#define QLD 1152   // row stride of fused qkv buffer
#define EXPSCALE 0.18033688f   // 0.125 * log2(e)

typedef __attribute__((ext_vector_type(8))) short short8;
typedef __attribute__((ext_vector_type(4))) float f32x4;

// element-index XOR swizzle for [R][64] ushort LDS tiles (8-elem groups)
#define SWZ(r, c) (((r) << 6) + ((c) ^ (((r) & 7) << 3)))

__device__ __forceinline__ ushort f2bf(float x) {
    unsigned u = __float_as_uint(x);
    u += 0x7FFF + ((u >> 16) & 1);
    return (ushort)(u >> 16);
}
__device__ __forceinline__ float bf2f(ushort u) {
    return __uint_as_float(((unsigned)u) << 16);
}
__device__ __forceinline__ short8 cvt8(const float* p) {
    short8 r;
    #pragma unroll
    for (int i = 0; i < 8; i++) r[i] = (short)f2bf(p[i]);
    return r;
}

// ---------------- fused f32->bf16 convert + depthwise conv (8 ch/thread) ----------------
__global__ __launch_bounds__(256) void cvt_dw_fused(
    const float* __restrict__ query, const float* __restrict__ dw_w,
    const float* __restrict__ dw_b, ushort* __restrict__ Xbf,
    ushort* __restrict__ dwout)
{
    int idx = blockIdx.x*256 + threadIdx.x;
    if (idx >= B*S*(HID/8)) return;
    int c0 = (idx % (HID/8))*8;
    int s  = (idx / (HID/8)) % S;
    int b  = idx / ((HID/8)*S);

    float ctr[8];
    *(float4*)&ctr[0] = *(const float4*)(query + ((size_t)b*S + s)*HID + c0);
    *(float4*)&ctr[4] = *(const float4*)(query + ((size_t)b*S + s)*HID + c0 + 4);
    *(short8*)(Xbf + ((size_t)b*S + s)*HID + c0) = cvt8(ctr);

    float acc[8];
    *(float4*)&acc[0] = *(const float4*)(dw_b + c0);
    *(float4*)&acc[4] = *(const float4*)(dw_b + c0 + 4);
    #pragma unroll
    for (int kk = 0; kk < KW; kk++) {
        int sp = s + kk - KW/2;
        if (sp >= 0 && sp < S) {
            float row[8];
            *(float4*)&row[0] = *(const float4*)(query + ((size_t)b*S + sp)*HID + c0);
            *(float4*)&row[4] = *(const float4*)(query + ((size_t)b*S + sp)*HID + c0 + 4);
            #pragma unroll
            for (int j = 0; j < 8; j++)
                acc[j] += row[j] * dw_w[(c0+j)*KW + kk];
        }
    }
    *(short8*)(dwout + ((size_t)b*S + s)*HID + c0) = cvt8(acc);
}

// ---------------- weight prep: bf16 transposed weights + fused qkv bias ----------------
__global__ __launch_bounds__(256) void prep_weights(
    const float* __restrict__ Wq, const float* __restrict__ Wk, const float* __restrict__ Wv,
    const float* __restrict__ bq, const float* __restrict__ bk, const float* __restrict__ bv,
    const float* __restrict__ pw_w, const float* __restrict__ Wsa,
    const float* __restrict__ Wda, const float* __restrict__ Wdk,
    ushort* __restrict__ WqkvT, ushort* __restrict__ pw_bf,
    ushort* __restrict__ WsaT, ushort* __restrict__ WdaT, ushort* __restrict__ WdkT,
    float* __restrict__ bqkv)
{
    int i = blockIdx.x*256 + threadIdx.x;
    if (i < 884736) {                          // WqkvT [1152][768]
        int n = i / 768, kk = i % 768;
        int w = n / 384, nn = n % 384;
        const float* W = (w == 0) ? Wq : (w == 1) ? Wk : Wv;
        WqkvT[i] = f2bf(W[kk*384 + nn]);
        return;
    }
    i -= 884736;
    if (i < 294912) { pw_bf[i] = f2bf(pw_w[i]); return; }   // [384][768] already [N][K]
    i -= 294912;
    if (i < 147456) {                          // WsaT [384][384]
        int n = i / 384, kk = i % 384;
        WsaT[i] = f2bf(Wsa[kk*384 + n]);
        return;
    }
    i -= 147456;
    if (i < 147456) {                          // WdaT [384][384]
        int n = i / 384, kk = i % 384;
        WdaT[i] = f2bf(Wda[kk*384 + n]);
        return;
    }
    i -= 147456;
    if (i < 49152) {                           // WdkT [128][384], rows >=54 zero
        int n = i / 384, kk = i % 384;
        WdkT[i] = (n < KNH) ? f2bf(Wdk[kk*KNH + n]) : (ushort)0;
        return;
    }
    i -= 49152;
    if (i < 1152) {                            // bqkv
        bqkv[i] = (i < 384) ? bq[i] : (i < 768) ? bk[i-384] : bv[i-768];
    }
}

// ---------------- bf16 MFMA GEMM, 128x128 tile, prefetch-pipelined ----------------
template<bool OUTBF>
__global__ __launch_bounds__(256) void gemm_mfma(
    const ushort* __restrict__ A, const ushort* __restrict__ Bt,
    const float* __restrict__ bias, void* __restrict__ Cout,
    int N, int Kd, int ldc)
{
    __shared__ __attribute__((aligned(16))) ushort As[128*32];
    __shared__ __attribute__((aligned(16))) ushort Bs[128*32];
    const int t = threadIdx.x;
    const int wave = t >> 6, lane = t & 63;
    const int lr = lane & 15, lg = lane >> 4;
    const int wr = wave >> 1, wc = wave & 1;
    const int bm = blockIdx.y * 128, bn = blockIdx.x * 128;

    f32x4 acc[4][4] = {};
    const int srow = t >> 1, sseg = t & 1;
    const ushort* Arow = A + (size_t)(bm + srow)*Kd + sseg*16;
    const ushort* Brow = Bt + (size_t)(bn + srow)*Kd + sseg*16;
    const int g0 = (sseg*2) ^ (srow & 3), g1 = (sseg*2 + 1) ^ (srow & 3);
    const int swz = lg ^ (lr & 3);

    short8 av0 = *(const short8*)(Arow);
    short8 av1 = *(const short8*)(Arow + 8);
    short8 bv0 = *(const short8*)(Brow);
    short8 bv1 = *(const short8*)(Brow + 8);

    for (int k0 = 0; k0 < Kd; k0 += 32) {
        __syncthreads();
        *(short8*)&As[srow*32 + g0*8] = av0;
        *(short8*)&As[srow*32 + g1*8] = av1;
        *(short8*)&Bs[srow*32 + g0*8] = bv0;
        *(short8*)&Bs[srow*32 + g1*8] = bv1;
        __syncthreads();
        if (k0 + 32 < Kd) {       // issue next-tile loads early (overlap with MFMA)
            av0 = *(const short8*)(Arow + k0 + 32);
            av1 = *(const short8*)(Arow + k0 + 40);
            bv0 = *(const short8*)(Brow + k0 + 32);
            bv1 = *(const short8*)(Brow + k0 + 40);
        }
        short8 af[4], bfr[4];
        #pragma unroll
        for (int m = 0; m < 4; m++)
            af[m] = *(const short8*)&As[(wr*64 + m*16 + lr)*32 + swz*8];
        #pragma unroll
        for (int n = 0; n < 4; n++)
            bfr[n] = *(const short8*)&Bs[(wc*64 + n*16 + lr)*32 + swz*8];
        #pragma unroll
        for (int m = 0; m < 4; m++)
            #pragma unroll
            for (int n = 0; n < 4; n++)
                acc[m][n] = __builtin_amdgcn_mfma_f32_16x16x32_bf16(af[m], bfr[n], acc[m][n], 0, 0, 0);
    }

    #pragma unroll
    for (int m = 0; m < 4; m++) {
        #pragma unroll
        for (int n = 0; n < 4; n++) {
            int gcol = bn + wc*64 + n*16 + lr;
            if (gcol >= N) continue;
            float bz = bias[gcol];
            #pragma unroll
            for (int r = 0; r < 4; r++) {
                size_t grow = bm + wr*64 + m*16 + lg*4 + r;
                float val = acc[m][n][r] + bz;
                if (OUTBF) ((ushort*)Cout)[grow*ldc + gcol] = f2bf(val);
                else       ((float*)Cout)[grow*ldc + gcol] = val;
            }
        }
    }
}

// ---------------- bf16 MFMA GEMM, 64x64 tile, dbuf-A + direct-B (1 barrier/iter) ----------------
// DUAL: blockIdx.z selects branch (0: A0/Bt0/bias0 -> C, 1: A1/Bt1/bias1 -> C+OUTHALF)
template<bool OUTBF, bool DUAL>
__global__ __launch_bounds__(256) void gemm64(
    const ushort* __restrict__ A0, const ushort* __restrict__ Bt0,
    const float* __restrict__ bias0, void* __restrict__ C0,
    const ushort* __restrict__ A1, const ushort* __restrict__ Bt1,
    const float* __restrict__ bias1,
    int N, int Kd, int ldc)
{
    __shared__ __attribute__((aligned(16))) ushort As[2][64*32];
    const ushort* A  = (DUAL && blockIdx.z) ? A1 : A0;
    const ushort* Bt = (DUAL && blockIdx.z) ? Bt1 : Bt0;
    const float* bias = (DUAL && blockIdx.z) ? bias1 : bias0;
    const int coff = (DUAL && blockIdx.z) ? OUTHALF : 0;

    const int t = threadIdx.x;
    const int wave = t >> 6, lane = t & 63;
    const int lr = lane & 15, lg = lane >> 4;
    const int wr = wave >> 1, wc = wave & 1;
    const int bm = blockIdx.y * 64, bn = blockIdx.x * 64;

    f32x4 acc[2][2] = {};
    const int srow = t >> 2, sseg = t & 3;
    const ushort* Arow = A + (size_t)(bm + srow)*Kd + sseg*8;
    const int gs = sseg ^ (srow & 3);
    const int swz = lg ^ (lr & 3);
    const ushort* Br0 = Bt + (size_t)(bn + wc*32 + lr)*Kd + lg*8;
    const ushort* Br1 = Br0 + (size_t)16*Kd;

    short8 av = *(const short8*)(Arow);
    *(short8*)&As[0][srow*32 + gs*8] = av;
    __syncthreads();
    int cur = 0;

    for (int k0 = 0; k0 < Kd; k0 += 32) {
        if (k0 + 32 < Kd) av = *(const short8*)(Arow + k0 + 32);
        short8 bfr0 = *(const short8*)(Br0 + k0);
        short8 bfr1 = *(const short8*)(Br1 + k0);
        short8 af[2];
        #pragma unroll
        for (int m = 0; m < 2; m++)
            af[m] = *(const short8*)&As[cur][(wr*32 + m*16 + lr)*32 + swz*8];
        #pragma unroll
        for (int m = 0; m < 2; m++) {
            acc[m][0] = __builtin_amdgcn_mfma_f32_16x16x32_bf16(af[m], bfr0, acc[m][0], 0, 0, 0);
            acc[m][1] = __builtin_amdgcn_mfma_f32_16x16x32_bf16(af[m], bfr1, acc[m][1], 0, 0, 0);
        }
        if (k0 + 32 < Kd)
            *(short8*)&As[cur^1][srow*32 + gs*8] = av;
        __syncthreads();
        cur ^= 1;
    }

    #pragma unroll
    for (int m = 0; m < 2; m++) {
        #pragma unroll
        for (int n = 0; n < 2; n++) {
            int gcol = bn + wc*32 + n*16 + lr;
            if (gcol >= N) continue;
            float bz = bias[gcol];
            #pragma unroll
            for (int r = 0; r < 4; r++) {
                size_t grow = bm + wr*32 + m*16 + lg*4 + r;
                float val = acc[m][n][r] + bz;
                if (OUTBF) ((ushort*)C0)[grow*ldc + gcol + coff] = f2bf(val);
                else       ((float*)C0)[grow*ldc + gcol + coff] = val;
            }
        }
    }
}

// ---------------- fused qks + dynamic-kernel GEMM (bf16 ksf) ----------------
__global__ __launch_bounds__(64) void gemm_qksdk(
    const ushort* __restrict__ qkv, const ushort* __restrict__ ksf,
    const ushort* __restrict__ WdkT, const float* __restrict__ bdk,
    float* __restrict__ dynlog)
{
    const int lane = threadIdx.x;
    const int lr = lane & 15, lg = lane >> 4;
    const int r0 = blockIdx.x * 16;
    const int row = r0 + lr;

    f32x4 acc[4] = {};
    for (int ks = 0; ks < RH/32; ks++) {
        int k0 = ks*32 + lg*8;
        short8 qv = *(const short8*)(qkv + (size_t)row*QLD + k0);
        short8 kv = *(const short8*)(ksf + (size_t)row*RH + k0);
        short8 afr;
        #pragma unroll
        for (int j = 0; j < 8; j++)
            afr[j] = (short)f2bf(bf2f((ushort)qv[j]) * bf2f((ushort)kv[j]));
        #pragma unroll
        for (int t4 = 0; t4 < 4; t4++) {
            short8 bfr = *(const short8*)(WdkT + (size_t)(t4*16 + lr)*RH + k0);
            acc[t4] = __builtin_amdgcn_mfma_f32_16x16x32_bf16(afr, bfr, acc[t4], 0, 0, 0);
        }
    }
    #pragma unroll
    for (int t4 = 0; t4 < 4; t4++) {
        int n = t4*16 + lr;
        if (n >= KNH) continue;
        float bz = bdk[n];
        #pragma unroll
        for (int r = 0; r < 4; r++)
            dynlog[(size_t)(r0 + lg*4 + r)*KNH + n] = acc[t4][r] + bz;
    }
}

// ---------------- fused attention: barrier-free pass A, dbuf-V pass B ----------------
__global__ __launch_bounds__(256) void attn_fused(
    const ushort* __restrict__ qkv, const int* __restrict__ mask,
    float* __restrict__ out0, ushort* __restrict__ attnws)
{
    __shared__ __attribute__((aligned(16))) ushort Vt[2][64*64];
    __shared__ __attribute__((aligned(16))) ushort Ps[4][16*64];

    // XCD-chunked swizzle: 768 blocks = 8 XCDs x 96; all q-tiles of a (b,h) on one XCD
    const int bid = blockIdx.x;
    const int wg = (bid & 7)*96 + (bid >> 3);
    const int q0 = (wg & 15)*64;
    const int h  = (wg >> 4) % NH;
    const int b  = wg / 96;

    const int t = threadIdx.x;
    const int wave = t >> 6, lane = t & 63;
    const int lr = lane & 15, lg = lane >> 4;

    const ushort* qrow = qkv + (size_t)(b*S + q0 + wave*16 + lr)*QLD + h*HD;
    short8 aQ0 = *(const short8*)(qrow + lg*8);
    short8 aQ1 = *(const short8*)(qrow + 32 + lg*8);

    const int srow = t >> 2;
    const int sseg = t & 3;
    const int* mrow = mask + b*S;
    const ushort* kfrag = qkv + RH + h*HD + (size_t)b*S*QLD;   // + row*QLD + col
    const ushort* vbase = qkv + 2*RH + (size_t)b*S*QLD + h*HD + srow;

    float lsum[4] = {0.f, 0.f, 0.f, 0.f};

    // ---------------- pass A: softmax denominators (no LDS, no barriers) ----------------
    for (int kc = 0; kc < S; kc += 64) {
        #pragma unroll
        for (int t4 = 0; t4 < 4; t4++) {
            const ushort* kr = kfrag + (size_t)(kc + t4*16 + lr)*QLD + lg*8;
            short8 b0 = *(const short8*)(kr);
            short8 b1 = *(const short8*)(kr + 32);
            f32x4 c = {0.f, 0.f, 0.f, 0.f};
            c = __builtin_amdgcn_mfma_f32_16x16x32_bf16(aQ0, b0, c, 0, 0, 0);
            c = __builtin_amdgcn_mfma_f32_16x16x32_bf16(aQ1, b1, c, 0, 0, 0);
            float add = mrow[kc + t4*16 + lr] ? 0.f : -1e30f;
            #pragma unroll
            for (int r = 0; r < 4; r++)
                lsum[r] += exp2f(c[r]*EXPSCALE + add);
        }
    }
    #pragma unroll
    for (int r = 0; r < 4; r++) {
        #pragma unroll
        for (int off = 1; off < 16; off <<= 1)
            lsum[r] += __shfl_xor(lsum[r], off, 16);
    }
    float inv[4];
    #pragma unroll
    for (int r = 0; r < 4; r++) inv[r] = 1.f / lsum[r];

    // ---------------- pass B: scores -> normalize -> out0, PV (dbuf Vt, 1 barrier/tile) ----------------
    f32x4 o[4] = {};
    ushort* Psw = &Ps[wave][0];
    const size_t obase = ((size_t)((b*NH + h)*S) + q0 + wave*16) * (size_t)S;

    {   // prologue: stage Vt[0]
        ushort vb[16];
        #pragma unroll
        for (int i = 0; i < 16; i++)
            vb[i] = vbase[(size_t)(sseg*16 + i)*QLD];
        *(short8*)&Vt[0][SWZ(srow, sseg*16)]     = *(short8*)&vb[0];
        *(short8*)&Vt[0][SWZ(srow, sseg*16 + 8)] = *(short8*)&vb[8];
    }
    __syncthreads();
    int cur = 0;

    for (int kc = 0; kc < S; kc += 64) {
        // issue next V^T gather early (hides under scores+PV)
        ushort vb[16];
        if (kc + 64 < S) {
            const ushort* vp = vbase + (size_t)(kc + 64)*QLD;
            #pragma unroll
            for (int i = 0; i < 16; i++)
                vb[i] = vp[(size_t)(sseg*16 + i)*QLD];
        }

        // scores: K frags direct from L2
        #pragma unroll
        for (int t4 = 0; t4 < 4; t4++) {
            const ushort* kr = kfrag + (size_t)(kc + t4*16 + lr)*QLD + lg*8;
            short8 b0 = *(const short8*)(kr);
            short8 b1 = *(const short8*)(kr + 32);
            f32x4 c = {0.f, 0.f, 0.f, 0.f};
            c = __builtin_amdgcn_mfma_f32_16x16x32_bf16(aQ0, b0, c, 0, 0, 0);
            c = __builtin_amdgcn_mfma_f32_16x16x32_bf16(aQ1, b1, c, 0, 0, 0);
            float add = mrow[kc + t4*16 + lr] ? 0.f : -1e30f;
            #pragma unroll
            for (int r = 0; r < 4; r++) {
                float p = exp2f(c[r]*EXPSCALE + add) * inv[r];
                __builtin_nontemporal_store(p, &out0[obase + (size_t)(lg*4 + r)*S + kc + t4*16 + lr]);
                Psw[SWZ(lg*4 + r, t4*16 + lr)] = f2bf(p);
            }
        }
        // PV from Vt[cur]
        #pragma unroll
        for (int kh = 0; kh < 2; kh++) {
            short8 pa = *(const short8*)&Psw[SWZ(lr, kh*32 + lg*8)];
            #pragma unroll
            for (int dt = 0; dt < 4; dt++) {
                short8 vv = *(const short8*)&Vt[cur][SWZ(dt*16 + lr, kh*32 + lg*8)];
                o[dt] = __builtin_amdgcn_mfma_f32_16x16x32_bf16(pa, vv, o[dt], 0, 0, 0);
            }
        }
        // write next Vt, single barrier
        if (kc + 64 < S) {
            *(short8*)&Vt[cur^1][SWZ(srow, sseg*16)]     = *(short8*)&vb[0];
            *(short8*)&Vt[cur^1][SWZ(srow, sseg*16 + 8)] = *(short8*)&vb[8];
        }
        __syncthreads();
        cur ^= 1;
    }

    #pragma unroll
    for (int dt = 0; dt < 4; dt++)
        #pragma unroll
        for (int r = 0; r < 4; r++)
            attnws[(size_t)(b*S + q0 + wave*16 + lg*4 + r)*RH + h*HD + dt*16 + lr] = f2bf(o[dt][r]);
}

// ---------------- dynamic conv: softmax over 9 taps + conv of v (4 ch/thread) ----------------
__global__ __launch_bounds__(256) void dyn_conv(
    const float* __restrict__ logits, const ushort* __restrict__ qkv,
    ushort* __restrict__ dynout)
{
    int idx = blockIdx.x*256 + threadIdx.x;
    if (idx >= B*S*(RH/4)) return;
    int r4 = (idx % (RH/4))*4;
    int s  = (idx / (RH/4)) % S;
    int b  = idx / ((RH/4)*S);
    int h  = r4 / HD;
    const float* lg = logits + ((size_t)b*S + s)*KNH + h*KW;
    float mx = lg[0];
    #pragma unroll
    for (int kk = 1; kk < KW; kk++) mx = fmaxf(mx, lg[kk]);
    float e[KW], sum = 0.f;
    #pragma unroll
    for (int kk = 0; kk < KW; kk++) { e[kk] = __expf(lg[kk]-mx); sum += e[kk]; }
    float inv = 1.f/sum;
    float acc[4] = {0.f, 0.f, 0.f, 0.f};
    const ushort* vbase = qkv + 2*RH;
    #pragma unroll
    for (int kk = 0; kk < KW; kk++) {
        int sp = s + kk - KW/2;
        if (sp >= 0 && sp < S) {
            const ushort* vp = vbase + (size_t)(b*S + sp)*QLD + r4;
            #pragma unroll
            for (int j = 0; j < 4; j++) acc[j] += bf2f(vp[j]) * e[kk];
        }
    }
    ushort4 o;
    o.x = f2bf(acc[0]*inv); o.y = f2bf(acc[1]*inv);
    o.z = f2bf(acc[2]*inv); o.w = f2bf(acc[3]*inv);
    *(ushort4*)(dynout + ((size_t)b*S + s)*RH + r4) = o;
}

extern "C" void kernel_launch(void* const* d_in, const int* in_sizes, int n_in,
                              void* d_out, int out_size, void* d_ws, size_t ws_size,
                              hipStream_t stream) {
    const float* query = (const float*)d_in[0];
    const int*   mask  = (const int*)d_in[1];
    const float* Wq    = (const float*)d_in[2];
    const float* bq    = (const float*)d_in[3];
    const float* Wk    = (const float*)d_in[4];
    const float* bk    = (const float*)d_in[5];
    const float* Wv    = (const float*)d_in[6];
    const float* bv    = (const float*)d_in[7];
    const float* dw_w  = (const float*)d_in[8];
    const float* dw_b  = (const float*)d_in[9];
    const float* pw_w  = (const float*)d_in[10];
    const float* pw_b  = (const float*)d_in[11];
    const float* Wsa   = (const float*)d_in[12];
    const float* bsa   = (const float*)d_in[13];
    const float* Wdk   = (const float*)d_in[14];
    const float* bdk   = (const float*)d_in[15];
    const float* Wda   = (const float*)d_in[16];
    const float* bda   = (const float*)d_in[17];

    float* out0 = (float*)d_out;                 // attn_wts [B,NH,S,S]
    float* out1 = out0 + (size_t)B*NH*S*S;       // concat [B,S,HID]

    char* wsb = (char*)d_ws;
    size_t off = 0;
    auto alloc = [&](size_t bytes) { char* p = wsb + off; off += (bytes + 255) & ~255ull; return p; };
    ushort* Xbf    = (ushort*)alloc((size_t)B*S*HID*2);
    ushort* qkvbf  = (ushort*)alloc((size_t)B*S*QLD*2);
    ushort* dwbf   = (ushort*)alloc((size_t)B*S*HID*2);
    ushort* ksf    = (ushort*)alloc((size_t)B*S*RH*2);
    ushort* attnbf = (ushort*)alloc((size_t)B*S*RH*2);
    ushort* dynbf  = (ushort*)alloc((size_t)B*S*RH*2);
    float*  dynlog = (float*) alloc((size_t)B*S*KNH*4);
    ushort* WqkvT  = (ushort*)alloc((size_t)QLD*HID*2);
    ushort* pw_bf  = (ushort*)alloc((size_t)RH*HID*2);
    ushort* WsaT   = (ushort*)alloc((size_t)RH*RH*2);
    ushort* WdaT   = (ushort*)alloc((size_t)RH*RH*2);
    ushort* WdkT   = (ushort*)alloc((size_t)128*RH*2);
    float*  bqkv   = (float*) alloc((size_t)QLD*4);

    const int M = B*S;  // 8192

    prep_weights<<<(1524864 + 255)/256, 256, 0, stream>>>(
        Wq, Wk, Wv, bq, bk, bv, pw_w, Wsa, Wda, Wdk,
        WqkvT, pw_bf, WsaT, WdaT, WdkT, bqkv);

    // fused bf16 convert + depthwise conv
    cvt_dw_fused<<<(M*(HID/8) + 255)/256, 256, 0, stream>>>(query, dw_w, dw_b, Xbf, dwbf);

    // fused qkv projection -> bf16 [M, 1152]
    gemm_mfma<true><<<dim3(QLD/128, M/128), 256, 0, stream>>>(
        Xbf, WqkvT, bqkv, qkvbf, QLD, HID, QLD);

    // pointwise conv GEMM -> ksf bf16
    gemm64<true, false><<<dim3(RH/64, M/64), 256, 0, stream>>>(
        dwbf, pw_bf, pw_b, ksf, nullptr, nullptr, nullptr, RH, HID, RH);

    // fused MFMA attention (768 blocks, XCD-chunked)
    attn_fused<<<dim3(768), 256, 0, stream>>>(qkvbf, mask, out0, attnbf);

    // fused qks + dynamic-kernel logits GEMM
    gemm_qksdk<<<M/16, 64, 0, stream>>>(qkvbf, ksf, WdkT, bdk, dynlog);

    // dynamic conv
    dyn_conv<<<(M*(RH/4) + 255)/256, 256, 0, stream>>>(dynlog, qkvbf, dynbf);

    // dual output projection: out1[:, :384] = attnbf@WsaT, out1[:, 384:] = dynbf@WdaT
    gemm64<false, true><<<dim3(OUTHALF/64, M/64, 2), 256, 0, stream>>>(
        attnbf, WsaT, bsa, out1, dynbf, WdaT, bda, OUTHALF, RH, HID);
}

// Round 9
// 299.508 us; speedup vs baseline: 1.1528x; 1.1528x over previous
//
#include <hip/hip_runtime.h>
#include <math.h>

#define B 8
#define S 1024
#define HID 768
#define RH 384
#define NH 6
#define HD 64
#define KW 9
#define KNH 54
#define OUTHALF 384
#define QLD 1152   // row stride of fused qkv buffer
#define EXPSCALE 0.18033688f   // 0.125 * log2(e)

typedef __attribute__((ext_vector_type(8))) short short8;
typedef __attribute__((ext_vector_type(4))) float f32x4;

// element-index XOR swizzle for [R][64] ushort LDS tiles (8-elem groups)
#define SWZ(r, c) (((r) << 6) + ((c) ^ (((r) & 7) << 3)))

__device__ __forceinline__ ushort f2bf(float x) {
    unsigned u = __float_as_uint(x);
    u += 0x7FFF + ((u >> 16) & 1);
    return (ushort)(u >> 16);
}
__device__ __forceinline__ float bf2f(ushort u) {
    return __uint_as_float(((unsigned)u) << 16);
}
__device__ __forceinline__ short8 cvt8(const float* p) {
    short8 r;
    #pragma unroll
    for (int i = 0; i < 8; i++) r[i] = (short)f2bf(p[i]);
    return r;
}

// ---------------- fused f32->bf16 convert + depthwise conv (8 ch/thread) ----------------
__global__ __launch_bounds__(256) void cvt_dw_fused(
    const float* __restrict__ query, const float* __restrict__ dw_w,
    const float* __restrict__ dw_b, ushort* __restrict__ Xbf,
    ushort* __restrict__ dwout)
{
    int idx = blockIdx.x*256 + threadIdx.x;
    if (idx >= B*S*(HID/8)) return;
    int c0 = (idx % (HID/8))*8;
    int s  = (idx / (HID/8)) % S;
    int b  = idx / ((HID/8)*S);

    float ctr[8];
    *(float4*)&ctr[0] = *(const float4*)(query + ((size_t)b*S + s)*HID + c0);
    *(float4*)&ctr[4] = *(const float4*)(query + ((size_t)b*S + s)*HID + c0 + 4);
    *(short8*)(Xbf + ((size_t)b*S + s)*HID + c0) = cvt8(ctr);

    float acc[8];
    *(float4*)&acc[0] = *(const float4*)(dw_b + c0);
    *(float4*)&acc[4] = *(const float4*)(dw_b + c0 + 4);
    #pragma unroll
    for (int kk = 0; kk < KW; kk++) {
        int sp = s + kk - KW/2;
        if (sp >= 0 && sp < S) {
            float row[8];
            *(float4*)&row[0] = *(const float4*)(query + ((size_t)b*S + sp)*HID + c0);
            *(float4*)&row[4] = *(const float4*)(query + ((size_t)b*S + sp)*HID + c0 + 4);
            #pragma unroll
            for (int j = 0; j < 8; j++)
                acc[j] += row[j] * dw_w[(c0+j)*KW + kk];
        }
    }
    *(short8*)(dwout + ((size_t)b*S + s)*HID + c0) = cvt8(acc);
}

// ---------------- weight prep: bf16 transposed weights + fused qkv bias ----------------
__global__ __launch_bounds__(256) void prep_weights(
    const float* __restrict__ Wq, const float* __restrict__ Wk, const float* __restrict__ Wv,
    const float* __restrict__ bq, const float* __restrict__ bk, const float* __restrict__ bv,
    const float* __restrict__ pw_w, const float* __restrict__ Wsa,
    const float* __restrict__ Wda, const float* __restrict__ Wdk,
    ushort* __restrict__ WqkvT, ushort* __restrict__ pw_bf,
    ushort* __restrict__ WsaT, ushort* __restrict__ WdaT, ushort* __restrict__ WdkT,
    float* __restrict__ bqkv)
{
    int i = blockIdx.x*256 + threadIdx.x;
    if (i < 884736) {                          // WqkvT [1152][768]
        int n = i / 768, kk = i % 768;
        int w = n / 384, nn = n % 384;
        const float* W = (w == 0) ? Wq : (w == 1) ? Wk : Wv;
        WqkvT[i] = f2bf(W[kk*384 + nn]);
        return;
    }
    i -= 884736;
    if (i < 294912) { pw_bf[i] = f2bf(pw_w[i]); return; }   // [384][768] already [N][K]
    i -= 294912;
    if (i < 147456) {                          // WsaT [384][384]
        int n = i / 384, kk = i % 384;
        WsaT[i] = f2bf(Wsa[kk*384 + n]);
        return;
    }
    i -= 147456;
    if (i < 147456) {                          // WdaT [384][384]
        int n = i / 384, kk = i % 384;
        WdaT[i] = f2bf(Wda[kk*384 + n]);
        return;
    }
    i -= 147456;
    if (i < 49152) {                           // WdkT [128][384], rows >=54 zero
        int n = i / 384, kk = i % 384;
        WdkT[i] = (n < KNH) ? f2bf(Wdk[kk*KNH + n]) : (ushort)0;
        return;
    }
    i -= 49152;
    if (i < 1152) {                            // bqkv
        bqkv[i] = (i < 384) ? bq[i] : (i < 768) ? bk[i-384] : bv[i-768];
    }
}

// ---------------- bf16 MFMA GEMM, 128x128 tile, prefetch-pipelined ----------------
template<bool OUTBF>
__global__ __launch_bounds__(256) void gemm_mfma(
    const ushort* __restrict__ A, const ushort* __restrict__ Bt,
    const float* __restrict__ bias, void* __restrict__ Cout,
    int N, int Kd, int ldc)
{
    __shared__ __attribute__((aligned(16))) ushort As[128*32];
    __shared__ __attribute__((aligned(16))) ushort Bs[128*32];
    const int t = threadIdx.x;
    const int wave = t >> 6, lane = t & 63;
    const int lr = lane & 15, lg = lane >> 4;
    const int wr = wave >> 1, wc = wave & 1;
    const int bm = blockIdx.y * 128, bn = blockIdx.x * 128;

    f32x4 acc[4][4] = {};
    const int srow = t >> 1, sseg = t & 1;
    const ushort* Arow = A + (size_t)(bm + srow)*Kd + sseg*16;
    const ushort* Brow = Bt + (size_t)(bn + srow)*Kd + sseg*16;
    const int g0 = (sseg*2) ^ (srow & 3), g1 = (sseg*2 + 1) ^ (srow & 3);
    const int swz = lg ^ (lr & 3);

    short8 av0 = *(const short8*)(Arow);
    short8 av1 = *(const short8*)(Arow + 8);
    short8 bv0 = *(const short8*)(Brow);
    short8 bv1 = *(const short8*)(Brow + 8);

    for (int k0 = 0; k0 < Kd; k0 += 32) {
        __syncthreads();
        *(short8*)&As[srow*32 + g0*8] = av0;
        *(short8*)&As[srow*32 + g1*8] = av1;
        *(short8*)&Bs[srow*32 + g0*8] = bv0;
        *(short8*)&Bs[srow*32 + g1*8] = bv1;
        __syncthreads();
        if (k0 + 32 < Kd) {
            av0 = *(const short8*)(Arow + k0 + 32);
            av1 = *(const short8*)(Arow + k0 + 40);
            bv0 = *(const short8*)(Brow + k0 + 32);
            bv1 = *(const short8*)(Brow + k0 + 40);
        }
        short8 af[4], bfr[4];
        #pragma unroll
        for (int m = 0; m < 4; m++)
            af[m] = *(const short8*)&As[(wr*64 + m*16 + lr)*32 + swz*8];
        #pragma unroll
        for (int n = 0; n < 4; n++)
            bfr[n] = *(const short8*)&Bs[(wc*64 + n*16 + lr)*32 + swz*8];
        #pragma unroll
        for (int m = 0; m < 4; m++)
            #pragma unroll
            for (int n = 0; n < 4; n++)
                acc[m][n] = __builtin_amdgcn_mfma_f32_16x16x32_bf16(af[m], bfr[n], acc[m][n], 0, 0, 0);
    }

    #pragma unroll
    for (int m = 0; m < 4; m++) {
        #pragma unroll
        for (int n = 0; n < 4; n++) {
            int gcol = bn + wc*64 + n*16 + lr;
            if (gcol >= N) continue;
            float bz = bias[gcol];
            #pragma unroll
            for (int r = 0; r < 4; r++) {
                size_t grow = bm + wr*64 + m*16 + lg*4 + r;
                float val = acc[m][n][r] + bz;
                if (OUTBF) ((ushort*)Cout)[grow*ldc + gcol] = f2bf(val);
                else       ((float*)Cout)[grow*ldc + gcol] = val;
            }
        }
    }
}

// ---------------- bf16 MFMA GEMM, 64x64 tile (round-5 version) ----------------
template<bool OUTBF, bool DUAL>
__global__ __launch_bounds__(256) void gemm64(
    const ushort* __restrict__ A0, const ushort* __restrict__ Bt0,
    const float* __restrict__ bias0, void* __restrict__ C0,
    const ushort* __restrict__ A1, const ushort* __restrict__ Bt1,
    const float* __restrict__ bias1,
    int N, int Kd, int ldc)
{
    __shared__ __attribute__((aligned(16))) ushort As[64*32];
    __shared__ __attribute__((aligned(16))) ushort Bs[64*32];
    const ushort* A  = (DUAL && blockIdx.z) ? A1 : A0;
    const ushort* Bt = (DUAL && blockIdx.z) ? Bt1 : Bt0;
    const float* bias = (DUAL && blockIdx.z) ? bias1 : bias0;
    const int coff = (DUAL && blockIdx.z) ? OUTHALF : 0;

    const int t = threadIdx.x;
    const int wave = t >> 6, lane = t & 63;
    const int lr = lane & 15, lg = lane >> 4;
    const int wr = wave >> 1, wc = wave & 1;
    const int bm = blockIdx.y * 64, bn = blockIdx.x * 64;

    f32x4 acc[2][2] = {};
    const int srow = t >> 2, sseg = t & 3;
    const ushort* Arow = A + (size_t)(bm + srow)*Kd + sseg*8;
    const ushort* Brow = Bt + (size_t)(bn + srow)*Kd + sseg*8;
    const int gs = sseg ^ (srow & 3);
    const int swz = lg ^ (lr & 3);

    short8 av = *(const short8*)(Arow);
    short8 bv = *(const short8*)(Brow);

    for (int k0 = 0; k0 < Kd; k0 += 32) {
        __syncthreads();
        *(short8*)&As[srow*32 + gs*8] = av;
        *(short8*)&Bs[srow*32 + gs*8] = bv;
        __syncthreads();
        if (k0 + 32 < Kd) {
            av = *(const short8*)(Arow + k0 + 32);
            bv = *(const short8*)(Brow + k0 + 32);
        }
        short8 af[2], bfr[2];
        #pragma unroll
        for (int m = 0; m < 2; m++)
            af[m] = *(const short8*)&As[(wr*32 + m*16 + lr)*32 + swz*8];
        #pragma unroll
        for (int n = 0; n < 2; n++)
            bfr[n] = *(const short8*)&Bs[(wc*32 + n*16 + lr)*32 + swz*8];
        #pragma unroll
        for (int m = 0; m < 2; m++)
            #pragma unroll
            for (int n = 0; n < 2; n++)
                acc[m][n] = __builtin_amdgcn_mfma_f32_16x16x32_bf16(af[m], bfr[n], acc[m][n], 0, 0, 0);
    }

    #pragma unroll
    for (int m = 0; m < 2; m++) {
        #pragma unroll
        for (int n = 0; n < 2; n++) {
            int gcol = bn + wc*32 + n*16 + lr;
            if (gcol >= N) continue;
            float bz = bias[gcol];
            #pragma unroll
            for (int r = 0; r < 4; r++) {
                size_t grow = bm + wr*32 + m*16 + lg*4 + r;
                float val = acc[m][n][r] + bz;
                if (OUTBF) ((ushort*)C0)[grow*ldc + gcol + coff] = f2bf(val);
                else       ((float*)C0)[grow*ldc + gcol + coff] = val;
            }
        }
    }
}

// ---------------- fused qks + dynamic-kernel GEMM (bf16 ksf) ----------------
__global__ __launch_bounds__(64) void gemm_qksdk(
    const ushort* __restrict__ qkv, const ushort* __restrict__ ksf,
    const ushort* __restrict__ WdkT, const float* __restrict__ bdk,
    float* __restrict__ dynlog)
{
    const int lane = threadIdx.x;
    const int lr = lane & 15, lg = lane >> 4;
    const int r0 = blockIdx.x * 16;
    const int row = r0 + lr;

    f32x4 acc[4] = {};
    for (int ks = 0; ks < RH/32; ks++) {
        int k0 = ks*32 + lg*8;
        short8 qv = *(const short8*)(qkv + (size_t)row*QLD + k0);
        short8 kv = *(const short8*)(ksf + (size_t)row*RH + k0);
        short8 afr;
        #pragma unroll
        for (int j = 0; j < 8; j++)
            afr[j] = (short)f2bf(bf2f((ushort)qv[j]) * bf2f((ushort)kv[j]));
        #pragma unroll
        for (int t4 = 0; t4 < 4; t4++) {
            short8 bfr = *(const short8*)(WdkT + (size_t)(t4*16 + lr)*RH + k0);
            acc[t4] = __builtin_amdgcn_mfma_f32_16x16x32_bf16(afr, bfr, acc[t4], 0, 0, 0);
        }
    }
    #pragma unroll
    for (int t4 = 0; t4 < 4; t4++) {
        int n = t4*16 + lr;
        if (n >= KNH) continue;
        float bz = bdk[n];
        #pragma unroll
        for (int r = 0; r < 4; r++)
            dynlog[(size_t)(r0 + lg*4 + r)*KNH + n] = acc[t4][r] + bz;
    }
}

// ---------------- attention kernel A: QK^T -> exp -> Praw (bf16, unnormalized) + invbuf ----------------
__global__ __launch_bounds__(256) void attn_scores(
    const ushort* __restrict__ qkv, const int* __restrict__ mask,
    ushort* __restrict__ Praw, float* __restrict__ invbuf)
{
    __shared__ __attribute__((aligned(16))) ushort Ks[2][64*64];
    __shared__ __attribute__((aligned(16))) ushort Ps[4][16*64];

    const int b = blockIdx.z, h = blockIdx.y, q0 = blockIdx.x * 64;
    const int t = threadIdx.x;
    const int wave = t >> 6, lane = t & 63;
    const int lr = lane & 15, lg = lane >> 4;

    const ushort* qrow = qkv + (size_t)(b*S + q0 + wave*16 + lr)*QLD + h*HD;
    short8 aQ0 = *(const short8*)(qrow + lg*8);
    short8 aQ1 = *(const short8*)(qrow + 32 + lg*8);

    const int srow = t >> 2, sseg = t & 3;
    const int* mrow = mask + b*S;
    const ushort* krbase = qkv + RH + (size_t)(b*S + srow)*QLD + h*HD + sseg*16;
    ushort* Psw = &Ps[wave][0];
    const size_t prow0 = (size_t)(b*NH + h)*S + q0 + wave*16;

    float lsum[4] = {0.f, 0.f, 0.f, 0.f};

    {   // prologue: stage K[0]
        short8 k0v = *(const short8*)(krbase);
        short8 k1v = *(const short8*)(krbase + 8);
        *(short8*)&Ks[0][SWZ(srow, sseg*16)]     = k0v;
        *(short8*)&Ks[0][SWZ(srow, sseg*16 + 8)] = k1v;
    }
    __syncthreads();
    int cur = 0;

    for (int kc = 0; kc < S; kc += 64) {
        short8 nk0, nk1;
        if (kc + 64 < S) {
            const ushort* kr = krbase + (size_t)(kc + 64)*QLD;
            nk0 = *(const short8*)(kr);
            nk1 = *(const short8*)(kr + 8);
        }
        #pragma unroll
        for (int t4 = 0; t4 < 4; t4++) {
            short8 b0 = *(const short8*)&Ks[cur][SWZ(t4*16 + lr, lg*8)];
            short8 b1 = *(const short8*)&Ks[cur][SWZ(t4*16 + lr, 32 + lg*8)];
            f32x4 c = {0.f, 0.f, 0.f, 0.f};
            c = __builtin_amdgcn_mfma_f32_16x16x32_bf16(aQ0, b0, c, 0, 0, 0);
            c = __builtin_amdgcn_mfma_f32_16x16x32_bf16(aQ1, b1, c, 0, 0, 0);
            float add = mrow[kc + t4*16 + lr] ? 0.f : -1e30f;
            #pragma unroll
            for (int r = 0; r < 4; r++) {
                float p = exp2f(c[r]*EXPSCALE + add);
                lsum[r] += p;
                Psw[SWZ(lg*4 + r, t4*16 + lr)] = f2bf(p);
            }
        }
        {   // per-wave coalesced writeback Psw -> Praw (within-wave, no barrier needed)
            int row = lane & 15, seg = lane >> 4;
            short8 p0 = *(const short8*)&Psw[SWZ(row, seg*16)];
            short8 p1 = *(const short8*)&Psw[SWZ(row, seg*16 + 8)];
            ushort* gp = Praw + (prow0 + row)*S + kc + seg*16;
            *(short8*)gp       = p0;
            *(short8*)(gp + 8) = p1;
        }
        if (kc + 64 < S) {
            *(short8*)&Ks[cur^1][SWZ(srow, sseg*16)]     = nk0;
            *(short8*)&Ks[cur^1][SWZ(srow, sseg*16 + 8)] = nk1;
        }
        __syncthreads();
        cur ^= 1;
    }

    #pragma unroll
    for (int r = 0; r < 4; r++) {
        #pragma unroll
        for (int off = 1; off < 16; off <<= 1)
            lsum[r] += __shfl_xor(lsum[r], off, 16);
    }
    if (lr == 0) {
        #pragma unroll
        for (int r = 0; r < 4; r++)
            invbuf[prow0 + lg*4 + r] = 1.f / lsum[r];
    }
}

// ---------------- attention kernel B: Praw -> out0 (normalized f32) + PV -> attnbf ----------------
__global__ __launch_bounds__(256) void attn_pv(
    const ushort* __restrict__ qkv, const ushort* __restrict__ Praw,
    const float* __restrict__ invbuf, float* __restrict__ out0,
    ushort* __restrict__ attnbf)
{
    __shared__ __attribute__((aligned(16))) ushort Pt[2][64*64];
    __shared__ __attribute__((aligned(16))) ushort Vt[2][64*64];

    const int b = blockIdx.z, h = blockIdx.y, q0 = blockIdx.x * 64;
    const int t = threadIdx.x;
    const int wave = t >> 6, lane = t & 63;
    const int lr = lane & 15, lg = lane >> 4;
    const int srow = t >> 2, sseg = t & 3;

    const size_t rbase = (size_t)(b*NH + h)*S + q0;
    const ushort* prbase = Praw + (rbase + srow)*S + sseg*16;   // + kc
    const ushort* vbase  = qkv + 2*RH + (size_t)b*S*QLD + h*HD + srow;

    const float inv_c = invbuf[rbase + wave*16 + lr];           // for out0 (row wave*16+lr)
    float inv_o[4];
    #pragma unroll
    for (int r = 0; r < 4; r++) inv_o[r] = invbuf[rbase + wave*16 + lg*4 + r];

    {   // prologue: stage Pt[0], Vt[0]
        short8 p0 = *(const short8*)(prbase);
        short8 p1 = *(const short8*)(prbase + 8);
        ushort vb[16];
        #pragma unroll
        for (int i = 0; i < 16; i++)
            vb[i] = vbase[(size_t)(sseg*16 + i)*QLD];
        *(short8*)&Pt[0][SWZ(srow, sseg*16)]     = p0;
        *(short8*)&Pt[0][SWZ(srow, sseg*16 + 8)] = p1;
        *(short8*)&Vt[0][SWZ(srow, sseg*16)]     = *(short8*)&vb[0];
        *(short8*)&Vt[0][SWZ(srow, sseg*16 + 8)] = *(short8*)&vb[8];
    }
    __syncthreads();
    int cur = 0;

    f32x4 o[4] = {};
    const size_t orow = (rbase + wave*16 + lr)*(size_t)S;       // out0 row for this lane

    for (int kc = 0; kc < S; kc += 64) {
        short8 np0, np1;
        ushort vb[16];
        if (kc + 64 < S) {
            np0 = *(const short8*)(prbase + kc + 64);
            np1 = *(const short8*)(prbase + kc + 72);
            const ushort* vp = vbase + (size_t)(kc + 64)*QLD;
            #pragma unroll
            for (int i = 0; i < 16; i++)
                vb[i] = vp[(size_t)(sseg*16 + i)*QLD];
        }

        #pragma unroll
        for (int kh = 0; kh < 2; kh++) {
            // A-operand: this wave's 16-row slice of the 64-row P tile
            short8 pa = *(const short8*)&Pt[cur][SWZ(wave*16 + lr, kh*32 + lg*8)];
            // normalized f32 writes to out0 (32B/lane, nontemporal)
            float pf[8];
            #pragma unroll
            for (int j = 0; j < 8; j++) pf[j] = bf2f((ushort)pa[j]) * inv_c;
            float* op = out0 + orow + kc + kh*32 + lg*8;
            __builtin_nontemporal_store(*(f32x4*)&pf[0], (f32x4*)op);
            __builtin_nontemporal_store(*(f32x4*)&pf[4], (f32x4*)(op + 4));
            // PV
            #pragma unroll
            for (int dt = 0; dt < 4; dt++) {
                short8 vv = *(const short8*)&Vt[cur][SWZ(dt*16 + lr, kh*32 + lg*8)];
                o[dt] = __builtin_amdgcn_mfma_f32_16x16x32_bf16(pa, vv, o[dt], 0, 0, 0);
            }
        }

        if (kc + 64 < S) {
            *(short8*)&Pt[cur^1][SWZ(srow, sseg*16)]     = np0;
            *(short8*)&Pt[cur^1][SWZ(srow, sseg*16 + 8)] = np1;
            *(short8*)&Vt[cur^1][SWZ(srow, sseg*16)]     = *(short8*)&vb[0];
            *(short8*)&Vt[cur^1][SWZ(srow, sseg*16 + 8)] = *(short8*)&vb[8];
        }
        __syncthreads();
        cur ^= 1;
    }

    #pragma unroll
    for (int dt = 0; dt < 4; dt++)
        #pragma unroll
        for (int r = 0; r < 4; r++)
            attnbf[(size_t)(b*S + q0 + wave*16 + lg*4 + r)*RH + h*HD + dt*16 + lr] =
                f2bf(o[dt][r] * inv_o[r]);
}

// ---------------- dynamic conv: softmax over 9 taps + conv of v (4 ch/thread) ----------------
__global__ __launch_bounds__(256) void dyn_conv(
    const float* __restrict__ logits, const ushort* __restrict__ qkv,
    ushort* __restrict__ dynout)
{
    int idx = blockIdx.x*256 + threadIdx.x;
    if (idx >= B*S*(RH/4)) return;
    int r4 = (idx % (RH/4))*4;
    int s  = (idx / (RH/4)) % S;
    int b  = idx / ((RH/4)*S);
    int h  = r4 / HD;
    const float* lg = logits + ((size_t)b*S + s)*KNH + h*KW;
    float mx = lg[0];
    #pragma unroll
    for (int kk = 1; kk < KW; kk++) mx = fmaxf(mx, lg[kk]);
    float e[KW], sum = 0.f;
    #pragma unroll
    for (int kk = 0; kk < KW; kk++) { e[kk] = __expf(lg[kk]-mx); sum += e[kk]; }
    float inv = 1.f/sum;
    float acc[4] = {0.f, 0.f, 0.f, 0.f};
    const ushort* vbase = qkv + 2*RH;
    #pragma unroll
    for (int kk = 0; kk < KW; kk++) {
        int sp = s + kk - KW/2;
        if (sp >= 0 && sp < S) {
            const ushort* vp = vbase + (size_t)(b*S + sp)*QLD + r4;
            #pragma unroll
            for (int j = 0; j < 4; j++) acc[j] += bf2f(vp[j]) * e[kk];
        }
    }
    ushort4 o;
    o.x = f2bf(acc[0]*inv); o.y = f2bf(acc[1]*inv);
    o.z = f2bf(acc[2]*inv); o.w = f2bf(acc[3]*inv);
    *(ushort4*)(dynout + ((size_t)b*S + s)*RH + r4) = o;
}

extern "C" void kernel_launch(void* const* d_in, const int* in_sizes, int n_in,
                              void* d_out, int out_size, void* d_ws, size_t ws_size,
                              hipStream_t stream) {
    const float* query = (const float*)d_in[0];
    const int*   mask  = (const int*)d_in[1];
    const float* Wq    = (const float*)d_in[2];
    const float* bq    = (const float*)d_in[3];
    const float* Wk    = (const float*)d_in[4];
    const float* bk    = (const float*)d_in[5];
    const float* Wv    = (const float*)d_in[6];
    const float* bv    = (const float*)d_in[7];
    const float* dw_w  = (const float*)d_in[8];
    const float* dw_b  = (const float*)d_in[9];
    const float* pw_w  = (const float*)d_in[10];
    const float* pw_b  = (const float*)d_in[11];
    const float* Wsa   = (const float*)d_in[12];
    const float* bsa   = (const float*)d_in[13];
    const float* Wdk   = (const float*)d_in[14];
    const float* bdk   = (const float*)d_in[15];
    const float* Wda   = (const float*)d_in[16];
    const float* bda   = (const float*)d_in[17];

    float* out0 = (float*)d_out;                 // attn_wts [B,NH,S,S]
    float* out1 = out0 + (size_t)B*NH*S*S;       // concat [B,S,HID]

    char* wsb = (char*)d_ws;
    size_t off = 0;
    auto alloc = [&](size_t bytes) { char* p = wsb + off; off += (bytes + 255) & ~255ull; return p; };
    ushort* Xbf    = (ushort*)alloc((size_t)B*S*HID*2);
    ushort* qkvbf  = (ushort*)alloc((size_t)B*S*QLD*2);
    ushort* dwbf   = (ushort*)alloc((size_t)B*S*HID*2);
    ushort* ksf    = (ushort*)alloc((size_t)B*S*RH*2);
    ushort* attnbf = (ushort*)alloc((size_t)B*S*RH*2);
    ushort* dynbf  = (ushort*)alloc((size_t)B*S*RH*2);
    float*  dynlog = (float*) alloc((size_t)B*S*KNH*4);
    ushort* WqkvT  = (ushort*)alloc((size_t)QLD*HID*2);
    ushort* pw_bf  = (ushort*)alloc((size_t)RH*HID*2);
    ushort* WsaT   = (ushort*)alloc((size_t)RH*RH*2);
    ushort* WdaT   = (ushort*)alloc((size_t)RH*RH*2);
    ushort* WdkT   = (ushort*)alloc((size_t)128*RH*2);
    float*  bqkv   = (float*) alloc((size_t)QLD*4);
    ushort* Praw   = (ushort*)alloc((size_t)B*NH*S*S*2);   // 100.7 MB unnormalized P
    float*  invbuf = (float*) alloc((size_t)B*NH*S*4);

    const int M = B*S;  // 8192

    prep_weights<<<(1524864 + 255)/256, 256, 0, stream>>>(
        Wq, Wk, Wv, bq, bk, bv, pw_w, Wsa, Wda, Wdk,
        WqkvT, pw_bf, WsaT, WdaT, WdkT, bqkv);

    // fused bf16 convert + depthwise conv
    cvt_dw_fused<<<(M*(HID/8) + 255)/256, 256, 0, stream>>>(query, dw_w, dw_b, Xbf, dwbf);

    // fused qkv projection -> bf16 [M, 1152]
    gemm_mfma<true><<<dim3(QLD/128, M/128), 256, 0, stream>>>(
        Xbf, WqkvT, bqkv, qkvbf, QLD, HID, QLD);

    // pointwise conv GEMM -> ksf bf16
    gemm64<true, false><<<dim3(RH/64, M/64), 256, 0, stream>>>(
        dwbf, pw_bf, pw_b, ksf, nullptr, nullptr, nullptr, RH, HID, RH);

    // attention: scores pass then PV/normalize pass
    attn_scores<<<dim3(S/64, NH, B), 256, 0, stream>>>(qkvbf, mask, Praw, invbuf);
    attn_pv<<<dim3(S/64, NH, B), 256, 0, stream>>>(qkvbf, Praw, invbuf, out0, attnbf);

    // fused qks + dynamic-kernel logits GEMM
    gemm_qksdk<<<M/16, 64, 0, stream>>>(qkvbf, ksf, WdkT, bdk, dynlog);

    // dynamic conv
    dyn_conv<<<(M*(RH/4) + 255)/256, 256, 0, stream>>>(dynlog, qkvbf, dynbf);

    // dual output projection: out1[:, :384] = attnbf@WsaT, out1[:, 384:] = dynbf@WdaT
    gemm64<false, true><<<dim3(OUTHALF/64, M/64, 2), 256, 0, stream>>>(
        attnbf, WsaT, bsa, out1, dynbf, WdaT, bda, OUTHALF, RH, HID);
}